// Round 1
// baseline (4875.784 us; speedup 1.0000x reference)
//
#include <hip/hip_runtime.h>

// MetaOptNet head: 15-iteration IPM QP (block-diagonal exploit: 10x 150x150) + logits.
// All f32. Deterministic (only u32 atomicMin used).

#define NW    10
#define NSH   15
#define NSUP  150
#define NQ    8192
#define DIM   1024
#define NVAR  1500
#define NP    152          // padded matrix dim (identity padding)
#define NTT   19           // 8x8 tiles per dim
#define NACT  (NTT*NTT)    // 361 active threads
#define TPB   384
#define SIGMA 0.1f

// ws offsets (in floats); total ~275,288 floats (~1.05 MB)
#define OFF_K     0
#define OFF_Z     22500
#define OFF_S     24000
#define OFF_LAM   25500
#define OFF_NU    27000
#define OFF_R1    27152
#define OFF_DZ    28652
#define OFF_DLAM  30152
#define OFF_DNU   31652
#define OFF_RP    31804
#define OFF_MU    31956
#define OFF_ALPHA 31957
#define OFF_LP    31960
#define OFF_WT    34008
#define OFF_X     44248
#define XSZ       (NP*NP)  // 23104

// ---------------- in-place Gauss-Jordan inversion, n=150 (within 152 pad) -------------
// Each thread owns an 8x8 register tile H[r][c] of the 152x152 matrix.
// Padding rows/cols hold identity and are provably untouched by the sweep.
__device__ __forceinline__ void gj_invert_150(float (&H)[8][8], int t, int tr, int tc,
                                              float* rowtmp, float* coltmp) {
  const bool act = (t < NACT);
  for (int k = 0; k < NSUP; ++k) {
    const int ktr = k >> 3;
    const int kr  = k & 7;
    if (act && tr == ktr) {
      switch (kr) {
#define ROWST(R) case R: {_Pragma("unroll") for (int c=0;c<8;++c) rowtmp[8*tc+c]=H[R][c];} break;
        ROWST(0) ROWST(1) ROWST(2) ROWST(3) ROWST(4) ROWST(5) ROWST(6) ROWST(7)
#undef ROWST
      }
    }
    if (act && tc == ktr) {
      switch (kr) {
#define COLST(C) case C: {_Pragma("unroll") for (int r=0;r<8;++r) coltmp[8*tr+r]=H[r][C];} break;
        COLST(0) COLST(1) COLST(2) COLST(3) COLST(4) COLST(5) COLST(6) COLST(7)
#undef COLST
      }
    }
    __syncthreads();
    if (act) {
      const float pinv = 1.0f / rowtmp[k];
      float cval[8], rsc[8];
#pragma unroll
      for (int r=0;r<8;++r) cval[r] = coltmp[8*tr+r];
#pragma unroll
      for (int c=0;c<8;++c) rsc[c]  = rowtmp[8*tc+c] * pinv;
#pragma unroll
      for (int r=0;r<8;++r)
#pragma unroll
        for (int c=0;c<8;++c)
          H[r][c] -= cval[r] * rsc[c];
      if (tr == ktr) {
        switch (kr) {
#define ROWOW(R) case R: {_Pragma("unroll") for (int c=0;c<8;++c) H[R][c]=rsc[c];} break;
          ROWOW(0) ROWOW(1) ROWOW(2) ROWOW(3) ROWOW(4) ROWOW(5) ROWOW(6) ROWOW(7)
#undef ROWOW
        }
      }
      if (tc == ktr) {
        switch (kr) {
#define COLOW(C) case C: {_Pragma("unroll") for (int r=0;r<8;++r) H[r][C] = -cval[r]*pinv;} break;
          COLOW(0) COLOW(1) COLOW(2) COLOW(3) COLOW(4) COLOW(5) COLOW(6) COLOW(7)
#undef COLOW
        }
      }
      if (tr == ktr && tc == ktr) {
        switch (kr) {
#define PIVOW(R) case R: H[R][R] = pinv; break;
          PIVOW(0) PIVOW(1) PIVOW(2) PIVOW(3) PIVOW(4) PIVOW(5) PIVOW(6) PIVOW(7)
#undef PIVOW
        }
      }
    }
    __syncthreads();
  }
}

// ---------------- K = support @ support^T (150x150), 15x15 tiles ----------------------
__global__ __launch_bounds__(256) void k_gram(const float* __restrict__ feat, float* __restrict__ ws) {
  const int bi = blockIdx.x / 10, bj = blockIdx.x % 10;
  const int t = threadIdx.x;
  const int r = t / 15, c = t % 15;
  const bool act = (t < 225);
  __shared__ float As[15][65], Bs[15][65];
  float acc = 0.0f;
  for (int ch = 0; ch < 16; ++ch) {
    for (int idx = t; idx < 960; idx += 256) {
      const int rr = idx >> 6, dd = idx & 63;
      As[rr][dd] = feat[(bi*15+rr)*DIM + ch*64 + dd];
      Bs[rr][dd] = feat[(bj*15+rr)*DIM + ch*64 + dd];
    }
    __syncthreads();
    if (act) {
      for (int dd = 0; dd < 64; ++dd) acc += As[r][dd] * Bs[c][dd];
    }
    __syncthreads();
  }
  if (act) ws[OFF_K + (bi*15+r)*NSUP + (bj*15+c)] = acc;
}

// ---------------- init: z=h-1, s=lam=1, nu=0, mu=1, rp -------------------------------
__global__ __launch_bounds__(1024) void kinit(const int* __restrict__ labSup, float* __restrict__ ws) {
  const int t = threadIdx.x;
  for (int idx = t; idx < NVAR; idx += 1024) {
    const int i = idx / NW, aa = idx % NW;
    const float y = (labSup[i/NSH] == aa) ? 1.0f : 0.0f;
    ws[OFF_Z+idx]   = 0.1f*y - 1.0f;
    ws[OFF_S+idx]   = 1.0f;
    ws[OFF_LAM+idx] = 1.0f;
  }
  if (t < NP) ws[OFF_NU + t] = 0.0f;
  if (t == 0) ws[OFF_MU] = 1.0f;
  if (t < NSUP) {
    float rpv = 0.0f;
    for (int aa = 0; aa < NW; ++aa) {
      const float y = (labSup[t/NSH] == aa) ? 1.0f : 0.0f;
      rpv += 0.1f*y - 1.0f;
    }
    ws[OFF_RP + t] = rpv;
  }
}

// ---------------- K1: per-way a: r1_a, invert H_a = K + 10I + diag(d_a) --------------
__global__ __launch_bounds__(TPB) void kqp1(const int* __restrict__ labSup, float* __restrict__ ws) {
  const int a = blockIdx.x;
  const int t = threadIdx.x;
  const int tr = t / NTT, tc = t % NTT;
  const bool act = (t < NACT);
  __shared__ float zloc[NP], dloc[NP], rowtmp[NP], coltmp[NP];
  __shared__ float pacc[NP][NTT];
  const float mu = ws[OFF_MU];
  for (int i = t; i < NP; i += TPB) {
    if (i < NSUP) {
      zloc[i] = ws[OFF_Z + i*NW + a];
      dloc[i] = ws[OFF_LAM + i*NW + a] / ws[OFF_S + i*NW + a];
    } else { zloc[i] = 0.0f; dloc[i] = 0.0f; }
  }
  __syncthreads();
  float H[8][8];
  if (act) {
#pragma unroll
    for (int r=0;r<8;++r) {
      const int row = 8*tr + r;
#pragma unroll
      for (int c=0;c<8;++c) {
        const int col = 8*tc + c;
        float v = (row < NSUP && col < NSUP) ? ws[OFF_K + row*NSUP + col] : 0.0f;
        if (row == col) v += (row < NSUP) ? (10.0f + dloc[row]) : 1.0f;
        H[r][c] = v;
      }
    }
#pragma unroll
    for (int r=0;r<8;++r) {
      float p = 0.0f;
#pragma unroll
      for (int c=0;c<8;++c) p += H[r][c] * zloc[8*tc + c];
      pacc[8*tr + r][tc] = p;   // (H z)_row partial; includes (10+d) z on diag
    }
  }
  __syncthreads();
  if (t < NSUP) {
    float hz = 0.0f;
    for (int q = 0; q < NTT; ++q) hz += pacc[t][q];
    const float qz  = hz - dloc[t]*zloc[t];                 // (K + 10I) z
    const float y   = (labSup[t/NSH] == a) ? 1.0f : 0.0f;
    const float svv = ws[OFF_S + t*NW+a], lvv = ws[OFF_LAM + t*NW+a];
    const float rd  = qz - y + lvv + ws[OFF_NU + t];        // p = -y
    const float rc  = svv*lvv - SIGMA*mu;
    ws[OFF_R1 + t*NW+a] = -rd + rc/svv;
  }
  gj_invert_150(H, t, tr, tc, rowtmp, coltmp);
  if (act) {
    float* Xa = ws + OFF_X + a*XSZ;
#pragma unroll
    for (int r=0;r<8;++r) {
      float4* dst = (float4*)(Xa + (8*tr+r)*NP + 8*tc);
      dst[0] = make_float4(H[r][0],H[r][1],H[r][2],H[r][3]);
      dst[1] = make_float4(H[r][4],H[r][5],H[r][6],H[r][7]);
    }
  }
}

// ---------------- K2: S = sum X_a; t = sum X_a r1_a + rp; dnu = S^-1 t ---------------
__global__ __launch_bounds__(TPB) void kqp2(float* __restrict__ ws) {
  const int t = threadIdx.x;
  const int tr = t / NTT, tc = t % NTT;
  const bool act = (t < NACT);
  __shared__ float r1loc[NVAR + 20];
  __shared__ float tloc[NP], rowtmp[NP], coltmp[NP];
  __shared__ float pacc[NP][NTT];
  for (int i = t; i < NVAR + 20; i += TPB) r1loc[i] = (i < NVAR) ? ws[OFF_R1 + i] : 0.0f;
  __syncthreads();
  float Sg[8][8]; float tg[8];
#pragma unroll
  for (int r=0;r<8;++r){ tg[r]=0.0f;
#pragma unroll
    for(int c=0;c<8;++c) Sg[r][c]=0.0f; }
  if (act) {
    for (int a = 0; a < NW; ++a) {
      const float* Xa = ws + OFF_X + a*XSZ;
      const int cb = 8*tc;
#pragma unroll
      for (int r=0;r<8;++r) {
        const float4* src = (const float4*)(Xa + (8*tr+r)*NP + cb);
        const float4 v0 = src[0], v1 = src[1];
        Sg[r][0]+=v0.x; Sg[r][1]+=v0.y; Sg[r][2]+=v0.z; Sg[r][3]+=v0.w;
        Sg[r][4]+=v1.x; Sg[r][5]+=v1.y; Sg[r][6]+=v1.z; Sg[r][7]+=v1.w;
        tg[r] += v0.x*r1loc[(cb+0)*NW+a] + v0.y*r1loc[(cb+1)*NW+a]
               + v0.z*r1loc[(cb+2)*NW+a] + v0.w*r1loc[(cb+3)*NW+a]
               + v1.x*r1loc[(cb+4)*NW+a] + v1.y*r1loc[(cb+5)*NW+a]
               + v1.z*r1loc[(cb+6)*NW+a] + v1.w*r1loc[(cb+7)*NW+a];
      }
    }
#pragma unroll
    for (int r=0;r<8;++r) pacc[8*tr+r][tc] = tg[r];
  }
  __syncthreads();
  if (t < NP) {
    float v = 0.0f;
    if (t < NSUP) { for (int q=0;q<NTT;++q) v += pacc[t][q]; v += ws[OFF_RP + t]; }
    tloc[t] = v;
  }
  __syncthreads();
  gj_invert_150(Sg, t, tr, tc, rowtmp, coltmp);
  if (act) {
#pragma unroll
    for (int r=0;r<8;++r) {
      float p = 0.0f;
#pragma unroll
      for (int c=0;c<8;++c) p += Sg[r][c]*tloc[8*tc+c];
      pacc[8*tr+r][tc] = p;
    }
  }
  __syncthreads();
  if (t < NP) {
    float v = 0.0f;
    if (t < NSUP) for (int q=0;q<NTT;++q) v += pacc[t][q];
    ws[OFF_DNU + t] = (t < NSUP) ? v : 0.0f;
  }
  if (t == 0) ((unsigned*)ws)[OFF_ALPHA] = 0x7F800000u;  // +inf
}

// ---------------- K3: dz_a = X_a (r1_a - dnu), dlam, step-length ratios --------------
__global__ __launch_bounds__(TPB) void kqp3(float* __restrict__ ws) {
  const int a = blockIdx.x;
  const int t = threadIdx.x;
  const int tr = t / NTT, tc = t % NTT;
  const bool act = (t < NACT);
  __shared__ float vloc[NP];
  __shared__ float pacc[NP][NTT];
  const float mu = ws[OFF_MU];
  for (int i = t; i < NP; i += TPB)
    vloc[i] = (i < NSUP) ? (ws[OFF_R1 + i*NW + a] - ws[OFF_DNU + i]) : 0.0f;
  __syncthreads();
  if (act) {
    const float* Xa = ws + OFF_X + a*XSZ;
    const int cb = 8*tc;
#pragma unroll
    for (int r=0;r<8;++r) {
      const float4* src = (const float4*)(Xa + (8*tr+r)*NP + cb);
      const float4 v0 = src[0], v1 = src[1];
      pacc[8*tr+r][tc] =
          v0.x*vloc[cb+0] + v0.y*vloc[cb+1] + v0.z*vloc[cb+2] + v0.w*vloc[cb+3]
        + v1.x*vloc[cb+4] + v1.y*vloc[cb+5] + v1.z*vloc[cb+6] + v1.w*vloc[cb+7];
    }
  }
  __syncthreads();
  if (t < NSUP) {
    float dzv = 0.0f;
    for (int q=0;q<NTT;++q) dzv += pacc[t][q];
    const float svv = ws[OFF_S + t*NW+a], lvv = ws[OFF_LAM + t*NW+a];
    const float rc  = svv*lvv - SIGMA*mu;
    const float dlv = (lvv*dzv - rc)/svv;
    ws[OFF_DZ + t*NW+a]   = dzv;
    ws[OFF_DLAM + t*NW+a] = dlv;
    unsigned* slot = (unsigned*)(ws) + OFF_ALPHA;
    const float dsv = -dzv;
    if (dsv < 0.0f) atomicMin(slot, __float_as_uint(-svv/dsv));
    if (dlv < 0.0f) atomicMin(slot, __float_as_uint(-lvv/dlv));
  }
}

// ---------------- K4: alpha, update z,s,lam,nu; next mu, rp --------------------------
__global__ __launch_bounds__(1024) void kqp4(float* __restrict__ ws) {
  const int t = threadIdx.x;
  __shared__ float zsh[NVAR];
  __shared__ float red[1024];
  const float am = __uint_as_float(((unsigned*)ws)[OFF_ALPHA]);
  const float alpha = fminf(1.0f, 0.99f * am);
  float part = 0.0f;
  for (int idx = t; idx < NVAR; idx += 1024) {
    const float dzv = ws[OFF_DZ + idx], dlv = ws[OFF_DLAM + idx];
    const float zn = ws[OFF_Z + idx]   + alpha*dzv;
    const float sn = ws[OFF_S + idx]   - alpha*dzv;
    const float ln = ws[OFF_LAM + idx] + alpha*dlv;
    ws[OFF_Z+idx]=zn; ws[OFF_S+idx]=sn; ws[OFF_LAM+idx]=ln;
    zsh[idx] = zn;
    part += sn*ln;
  }
  if (t < NSUP) ws[OFF_NU + t] += alpha * ws[OFF_DNU + t];
  red[t] = part;
  __syncthreads();
  for (int off = 512; off > 0; off >>= 1) {
    if (t < off) red[t] += red[t + off];
    __syncthreads();
  }
  if (t == 0) ws[OFF_MU] = red[0] / (float)NVAR;
  if (t < NSUP) {
    float rpv = 0.0f;
#pragma unroll
    for (int a=0;a<NW;++a) rpv += zsh[t*NW+a];
    ws[OFF_RP + t] = rpv;
  }
}

// ---------------- Wt[w][d] = scale * sum_s support[s][d] * z[s*10+w] -----------------
__global__ __launch_bounds__(1024) void k_wt(const float* __restrict__ feat,
                                             const float* __restrict__ scale,
                                             float* __restrict__ ws) {
  const int w = blockIdx.x;
  const int dd = threadIdx.x;
  float acc = 0.0f;
  for (int ss = 0; ss < NSUP; ++ss)
    acc += feat[ss*DIM + dd] * ws[OFF_Z + ss*NW + w];
  ws[OFF_WT + w*DIM + dd] = acc * scale[0];
}

// ---------------- logits + log_softmax + loss partials (wave per query row) ----------
__global__ __launch_bounds__(256) void k_logits(const float* __restrict__ feat,
                                                const int* __restrict__ labq,
                                                float* __restrict__ out,
                                                float* __restrict__ ws) {
  const int t = threadIdx.x;
  const int wv = t >> 6, l = t & 63;
  const int q = blockIdx.x*4 + wv;
  __shared__ float wtl[NW][DIM];
  __shared__ float lpart[4];
  for (int idx = t; idx < NW*DIM; idx += 256) wtl[idx >> 10][idx & 1023] = ws[OFF_WT + idx];
  __syncthreads();
  const float* qrow = feat + (size_t)(NSUP + q)*DIM;
  float acc[NW];
#pragma unroll
  for (int w=0;w<NW;++w) acc[w]=0.0f;
#pragma unroll
  for (int c = 0; c < 4; ++c) {
    const float4 qv = *(const float4*)(qrow + c*256 + 4*l);
#pragma unroll
    for (int w=0;w<NW;++w) {
      const float4 wvv = *(const float4*)(&wtl[w][c*256 + 4*l]);
      acc[w] += qv.x*wvv.x + qv.y*wvv.y + qv.z*wvv.z + qv.w*wvv.w;
    }
  }
#pragma unroll
  for (int w=0;w<NW;++w) {
#pragma unroll
    for (int off = 32; off > 0; off >>= 1)
      acc[w] += __shfl_xor(acc[w], off, 64);
  }
  float m = acc[0];
#pragma unroll
  for (int w=1;w<NW;++w) m = fmaxf(m, acc[w]);
  float se = 0.0f;
#pragma unroll
  for (int w=0;w<NW;++w) se += expf(acc[w]-m);
  const float lse = m + logf(se);
  const int y = labq[q];
  if (l == 0) {
    float lpy = 0.0f;
#pragma unroll
    for (int w=0;w<NW;++w) {
      const float lp = acc[w] - lse;
      out[q*NW + w] = lp;
      if (w == y) lpy = lp;
    }
    lpart[wv] = -lpy;
  }
  __syncthreads();
  if (t == 0) ws[OFF_LP + blockIdx.x] = lpart[0]+lpart[1]+lpart[2]+lpart[3];
}

__global__ __launch_bounds__(1024) void k_loss(float* __restrict__ out, const float* __restrict__ ws) {
  const int t = threadIdx.x;
  __shared__ float red[1024];
  red[t] = ws[OFF_LP + t] + ws[OFF_LP + 1024 + t];
  __syncthreads();
  for (int off = 512; off > 0; off >>= 1) {
    if (t < off) red[t] += red[t + off];
    __syncthreads();
  }
  if (t == 0) out[NQ*NW] = red[0] / (float)NQ;
}

extern "C" void kernel_launch(void* const* d_in, const int* in_sizes, int n_in,
                              void* d_out, int out_size, void* d_ws, size_t ws_size,
                              hipStream_t stream) {
  const float* feat  = (const float*)d_in[0];
  const int*   labS  = (const int*)d_in[1];
  const int*   labQ  = (const int*)d_in[2];
  const float* scale = (const float*)d_in[3];
  float* ws  = (float*)d_ws;
  float* out = (float*)d_out;

  k_gram<<<100, 256, 0, stream>>>(feat, ws);
  kinit<<<1, 1024, 0, stream>>>(labS, ws);
  for (int it = 0; it < 15; ++it) {
    kqp1<<<NW, TPB, 0, stream>>>(labS, ws);
    kqp2<<<1,  TPB, 0, stream>>>(ws);
    kqp3<<<NW, TPB, 0, stream>>>(ws);
    kqp4<<<1, 1024, 0, stream>>>(ws);
  }
  k_wt<<<NW, 1024, 0, stream>>>(feat, scale, ws);
  k_logits<<<NQ/4, 256, 0, stream>>>(feat, labQ, out, ws);
  k_loss<<<1, 1024, 0, stream>>>(out, ws);
}

// Round 2
// 2167.353 us; speedup vs baseline: 2.2496x; 2.2496x over previous
//
#include <hip/hip_runtime.h>

// MetaOptNet head: 15-iteration IPM QP (block-diagonal: 10x 150x150) + logits.
// Blocked (rank-8) Gauss-Jordan inversion, register-resident tiles, no spills.
// Deterministic (only u32 atomicMin used).

#define NW    10
#define NSH   15
#define NSUP  150
#define NQ    8192
#define DIM   1024
#define NVAR  1500
#define NP    152          // padded matrix dim (identity padding)
#define NTT   19           // 8x8 tiles per dim
#define NACT  (NTT*NTT)    // 361 active threads
#define TPB   384
#define SIGMA 0.1f
#define PSTR  68           // LDS panel row stride (64 + 4 pad, keeps 16B align, breaks bank aliasing)

// ws offsets (floats); total 300,192 floats (~1.2 MB)
#define OFF_K     0        // K stored [150][NP] (stride 152, float4-aligned rows)
#define OFF_Z     22800
#define OFF_S     24300
#define OFF_LAM   25800
#define OFF_NU    27300
#define OFF_R1    27452
#define OFF_DZ    28952
#define OFF_DLAM  30452
#define OFF_DNU   31952
#define OFF_RP    32104
#define OFF_MU    32256
#define OFF_ALPHA 32257
#define OFF_LP    32260
#define OFF_WT    34308
#define OFF_G     44548    // G[i*10+a] = (X_a r1_a)_i
#define OFF_SMAT  46048    // S = sum_a X_a  (152x152)
#define OFF_X     69152
#define XSZ       (NP*NP)  // 23104

// ---------------- blocked Gauss-Jordan inversion (19 rank-8 steps) -------------------
// Thread (tr,tc) owns 8x8 register tile H. Per block step kb:
//  B1: row-panel (tr==kb) and col-panel (tc==kb) tiles -> LDS
//  wave 0: invert 8x8 pivot P via shuffles -> pivinv LDS
//  threads t<152: W_j = Pinv * R_j (W_kb = Pinv) -> wbuf
//  all: interior H -= C * W; row panel H = W; col panel H = 0 - C*Pinv (via zero trick)
__device__ __forceinline__ void bgj_invert(float (&H)[8][8], const int t, const int tr, const int tc,
                                           float (*rowbuf)[PSTR], float (*colbuf)[PSTR],
                                           float (*wbuf)[PSTR], float* pivinv) {
  const bool act = (t < NACT);
  const int r8 = t & 7;
  const int wj = t >> 3;
  for (int kb = 0; kb < NTT; ++kb) {
    if (act && tr == kb) {
      float4* dst = (float4*)(&rowbuf[tc][0]);
#pragma unroll
      for (int r = 0; r < 8; ++r) {
        dst[2*r]   = make_float4(H[r][0],H[r][1],H[r][2],H[r][3]);
        dst[2*r+1] = make_float4(H[r][4],H[r][5],H[r][6],H[r][7]);
      }
    }
    if (act && tc == kb) {
      float4* dst = (float4*)(&colbuf[tr][0]);
#pragma unroll
      for (int r = 0; r < 8; ++r) {
        dst[2*r]   = make_float4(H[r][0],H[r][1],H[r][2],H[r][3]);
        dst[2*r+1] = make_float4(H[r][4],H[r][5],H[r][6],H[r][7]);
      }
    }
    __syncthreads();
    if (t < 64) {                       // wave 0: shuffle-based 8x8 GJ inverse
      const int r = t >> 3, c = t & 7;
      float p = rowbuf[kb][t];
#pragma unroll
      for (int pp = 0; pp < 8; ++pp) {
        const float pv   = __shfl(p, pp*9, 64);
        const float d    = 1.0f / pv;
        const float rowv = __shfl(p, pp*8 + c, 64);
        const float colv = __shfl(p, r*8 + pp, 64);
        const float nr   = rowv * d;
        float v = fmaf(-colv, nr, p);
        if (r == pp) v = nr;
        if (c == pp) v = -colv * d;
        if (r == pp && c == pp) v = d;
        p = v;
      }
      pivinv[t] = p;
    }
    __syncthreads();
    if (t < 8*NTT) {                    // W rows: thread = (r8, block-col wj)
      float w[8];
      if (wj == kb) {
#pragma unroll
        for (int c = 0; c < 8; ++c) w[c] = pivinv[r8*8+c];
      } else {
        const float4* rs = (const float4*)(&rowbuf[wj][0]);
#pragma unroll
        for (int c = 0; c < 8; ++c) w[c] = 0.0f;
#pragma unroll
        for (int q = 0; q < 8; ++q) {
          const float pq = pivinv[r8*8+q];
          const float4 x = rs[2*q], y = rs[2*q+1];
          w[0]=fmaf(pq,x.x,w[0]); w[1]=fmaf(pq,x.y,w[1]); w[2]=fmaf(pq,x.z,w[2]); w[3]=fmaf(pq,x.w,w[3]);
          w[4]=fmaf(pq,y.x,w[4]); w[5]=fmaf(pq,y.y,w[5]); w[6]=fmaf(pq,y.z,w[6]); w[7]=fmaf(pq,y.w,w[7]);
        }
      }
      float4* wd = (float4*)(&wbuf[wj][0]);
      wd[2*r8]   = make_float4(w[0],w[1],w[2],w[3]);
      wd[2*r8+1] = make_float4(w[4],w[5],w[6],w[7]);
    }
    __syncthreads();
    if (act) {
      if (tr == kb) {
        const float4* wsrc = (const float4*)(&wbuf[tc][0]);
#pragma unroll
        for (int r = 0; r < 8; ++r) {
          const float4 x = wsrc[2*r], y = wsrc[2*r+1];
          H[r][0]=x.x; H[r][1]=x.y; H[r][2]=x.z; H[r][3]=x.w;
          H[r][4]=y.x; H[r][5]=y.y; H[r][6]=y.z; H[r][7]=y.w;
        }
      } else {
        float C[8][8];
        const float4* cs = (const float4*)(&colbuf[tr][0]);
#pragma unroll
        for (int r = 0; r < 8; ++r) {
          const float4 x = cs[2*r], y = cs[2*r+1];
          C[r][0]=x.x; C[r][1]=x.y; C[r][2]=x.z; C[r][3]=x.w;
          C[r][4]=y.x; C[r][5]=y.y; C[r][6]=y.z; C[r][7]=y.w;
        }
        if (tc == kb) {
#pragma unroll
          for (int r = 0; r < 8; ++r)
#pragma unroll
            for (int c = 0; c < 8; ++c) H[r][c] = 0.0f;
        }
        const float4* wsrc = (const float4*)(&wbuf[tc][0]);
#pragma unroll
        for (int q = 0; q < 8; ++q) {
          const float4 x = wsrc[2*q], y = wsrc[2*q+1];
          const float w0=x.x,w1=x.y,w2=x.z,w3=x.w,w4=y.x,w5=y.y,w6=y.z,w7=y.w;
#pragma unroll
          for (int r = 0; r < 8; ++r) {
            const float cq = C[r][q];
            H[r][0]=fmaf(-cq,w0,H[r][0]); H[r][1]=fmaf(-cq,w1,H[r][1]);
            H[r][2]=fmaf(-cq,w2,H[r][2]); H[r][3]=fmaf(-cq,w3,H[r][3]);
            H[r][4]=fmaf(-cq,w4,H[r][4]); H[r][5]=fmaf(-cq,w5,H[r][5]);
            H[r][6]=fmaf(-cq,w6,H[r][6]); H[r][7]=fmaf(-cq,w7,H[r][7]);
          }
        }
      }
    }
    __syncthreads();
  }
}

// ---------------- K = support @ support^T (150x150, stride NP) -----------------------
__global__ __launch_bounds__(256) void k_gram(const float* __restrict__ feat, float* __restrict__ ws) {
  const int bi = blockIdx.x / 10, bj = blockIdx.x % 10;
  const int t = threadIdx.x;
  const int r = t / 15, c = t % 15;
  const bool act = (t < 225);
  __shared__ float As[15][65], Bs[15][65];
  float acc = 0.0f;
  for (int ch = 0; ch < 16; ++ch) {
    for (int idx = t; idx < 960; idx += 256) {
      const int rr = idx >> 6, dd = idx & 63;
      As[rr][dd] = feat[(bi*15+rr)*DIM + ch*64 + dd];
      Bs[rr][dd] = feat[(bj*15+rr)*DIM + ch*64 + dd];
    }
    __syncthreads();
    if (act) {
      for (int dd = 0; dd < 64; ++dd) acc += As[r][dd] * Bs[c][dd];
    }
    __syncthreads();
  }
  if (act) ws[OFF_K + (bi*15+r)*NP + (bj*15+c)] = acc;
}

// ---------------- init ----------------------------------------------------------------
__global__ __launch_bounds__(1024) void kinit(const int* __restrict__ labSup, float* __restrict__ ws) {
  const int t = threadIdx.x;
  for (int idx = t; idx < NVAR; idx += 1024) {
    const int i = idx / NW, aa = idx % NW;
    const float y = (labSup[i/NSH] == aa) ? 1.0f : 0.0f;
    ws[OFF_Z+idx]   = 0.1f*y - 1.0f;
    ws[OFF_S+idx]   = 1.0f;
    ws[OFF_LAM+idx] = 1.0f;
  }
  if (t < NP) ws[OFF_NU + t] = 0.0f;
  if (t == 0) ws[OFF_MU] = 1.0f;
  if (t < NSUP) {
    float rpv = 0.0f;
    for (int aa = 0; aa < NW; ++aa) {
      const float y = (labSup[t/NSH] == aa) ? 1.0f : 0.0f;
      rpv += 0.1f*y - 1.0f;
    }
    ws[OFF_RP + t] = rpv;
  }
}

// ---------------- K1: per-way: r1_a, X_a = H_a^{-1}, G_a = X_a r1_a -------------------
__global__ __launch_bounds__(TPB, 2) void kqp1(const int* __restrict__ labSup, float* __restrict__ ws) {
  const int a = blockIdx.x;
  const int t = threadIdx.x;
  const int tr = t / NTT, tc = t % NTT;
  const bool act = (t < NACT);
  __shared__ __align__(16) float rowbuf[NTT][PSTR], colbuf[NTT][PSTR], wbuf[NTT][PSTR];
  __shared__ __align__(16) float pivinv[64];
  __shared__ float zloc[NP], dloc[NP], r1loc[NP];
  __shared__ float pacc[NP][NTT];
  const float mu = ws[OFF_MU];
  for (int i = t; i < NP; i += TPB) {
    if (i < NSUP) {
      zloc[i] = ws[OFF_Z + i*NW + a];
      dloc[i] = ws[OFF_LAM + i*NW + a] / ws[OFF_S + i*NW + a];
    } else { zloc[i] = 0.0f; dloc[i] = 0.0f; }
  }
  __syncthreads();
  float H[8][8];
  if (act) {
#pragma unroll
    for (int r = 0; r < 8; ++r) {
      const int row = 8*tr + r;
      if (row < NSUP) {
        const float4* ks = (const float4*)(ws + OFF_K + row*NP + 8*tc);
        const float4 x = ks[0], y = ks[1];
        H[r][0]=x.x; H[r][1]=x.y; H[r][2]=x.z; H[r][3]=x.w;
        H[r][4]=y.x; H[r][5]=y.y; H[r][6]=y.z; H[r][7]=y.w;
        if (tc == NTT-1) { H[r][6] = 0.0f; H[r][7] = 0.0f; }   // K pad cols 150,151
      } else {
#pragma unroll
        for (int c = 0; c < 8; ++c) H[r][c] = 0.0f;
      }
#pragma unroll
      for (int c = 0; c < 8; ++c) {
        const int col = 8*tc + c;
        if (col == row) H[r][c] += (row < NSUP) ? (10.0f + dloc[row]) : 1.0f;
      }
    }
#pragma unroll
    for (int r = 0; r < 8; ++r) {
      float p = 0.0f;
#pragma unroll
      for (int c = 0; c < 8; ++c) p = fmaf(H[r][c], zloc[8*tc + c], p);
      pacc[8*tr + r][tc] = p;   // (H z) partials
    }
  }
  __syncthreads();
  if (t < NSUP) {
    float hz = 0.0f;
    for (int q = 0; q < NTT; ++q) hz += pacc[t][q];
    const float qz  = hz - dloc[t]*zloc[t];                 // (K + 10I) z
    const float y   = (labSup[t/NSH] == a) ? 1.0f : 0.0f;
    const float svv = ws[OFF_S + t*NW+a], lvv = ws[OFF_LAM + t*NW+a];
    const float rd  = qz - y + lvv + ws[OFF_NU + t];        // p = -y
    const float rc  = svv*lvv - SIGMA*mu;
    const float r1v = -rd + rc/svv;
    ws[OFF_R1 + t*NW+a] = r1v;
    r1loc[t] = r1v;
  }
  if (t >= NSUP && t < NP) r1loc[t] = 0.0f;
  bgj_invert(H, t, tr, tc, rowbuf, colbuf, wbuf, pivinv);
  if (act) {
    float* Xa = ws + OFF_X + a*XSZ;
#pragma unroll
    for (int r = 0; r < 8; ++r) {
      float4* dst = (float4*)(Xa + (8*tr+r)*NP + 8*tc);
      dst[0] = make_float4(H[r][0],H[r][1],H[r][2],H[r][3]);
      dst[1] = make_float4(H[r][4],H[r][5],H[r][6],H[r][7]);
    }
#pragma unroll
    for (int r = 0; r < 8; ++r) {
      float p = 0.0f;
#pragma unroll
      for (int c = 0; c < 8; ++c) p = fmaf(H[r][c], r1loc[8*tc+c], p);
      pacc[8*tr+r][tc] = p;     // (X_a r1_a) partials
    }
  }
  __syncthreads();
  if (t < NSUP) {
    float g = 0.0f;
    for (int q = 0; q < NTT; ++q) g += pacc[t][q];
    ws[OFF_G + t*NW + a] = g;
  }
}

// ---------------- k_sum: S = sum_a X_a (parallel across CUs) -------------------------
__global__ __launch_bounds__(256) void k_sum(float* __restrict__ ws) {
  for (int idx = blockIdx.x*256 + threadIdx.x; idx < XSZ; idx += gridDim.x*256) {
    float v = 0.0f;
#pragma unroll
    for (int a = 0; a < NW; ++a) v += ws[OFF_X + a*XSZ + idx];
    ws[OFF_SMAT + idx] = v;
  }
}

// ---------------- K2: invert S, dnu = S^{-1}(sum_a G_a + rp) -------------------------
__global__ __launch_bounds__(TPB, 2) void kqp2(float* __restrict__ ws) {
  const int t = threadIdx.x;
  const int tr = t / NTT, tc = t % NTT;
  const bool act = (t < NACT);
  __shared__ __align__(16) float rowbuf[NTT][PSTR], colbuf[NTT][PSTR], wbuf[NTT][PSTR];
  __shared__ __align__(16) float pivinv[64];
  __shared__ float tloc[NP];
  __shared__ float pacc[NP][NTT];
  float Sg[8][8];
  if (act) {
#pragma unroll
    for (int r = 0; r < 8; ++r) {
      const float4* ss = (const float4*)(ws + OFF_SMAT + (8*tr+r)*NP + 8*tc);
      const float4 x = ss[0], y = ss[1];
      Sg[r][0]=x.x; Sg[r][1]=x.y; Sg[r][2]=x.z; Sg[r][3]=x.w;
      Sg[r][4]=y.x; Sg[r][5]=y.y; Sg[r][6]=y.z; Sg[r][7]=y.w;
    }
  }
  if (t < NP) {
    float v = 0.0f;
    if (t < NSUP) {
      v = ws[OFF_RP + t];
#pragma unroll
      for (int a = 0; a < NW; ++a) v += ws[OFF_G + t*NW + a];
    }
    tloc[t] = v;
  }
  bgj_invert(Sg, t, tr, tc, rowbuf, colbuf, wbuf, pivinv);
  if (act) {
#pragma unroll
    for (int r = 0; r < 8; ++r) {
      float p = 0.0f;
#pragma unroll
      for (int c = 0; c < 8; ++c) p = fmaf(Sg[r][c], tloc[8*tc+c], p);
      pacc[8*tr+r][tc] = p;
    }
  }
  __syncthreads();
  if (t < NP) {
    float v = 0.0f;
    if (t < NSUP) for (int q = 0; q < NTT; ++q) v += pacc[t][q];
    ws[OFF_DNU + t] = v;
  }
  if (t == 0) ((unsigned*)ws)[OFF_ALPHA] = 0x7F800000u;  // +inf
}

// ---------------- K3: dz_a = X_a (r1_a - dnu), dlam, step-length ratios --------------
__global__ __launch_bounds__(TPB) void kqp3(float* __restrict__ ws) {
  const int a = blockIdx.x;
  const int t = threadIdx.x;
  const int tr = t / NTT, tc = t % NTT;
  const bool act = (t < NACT);
  __shared__ float vloc[NP];
  __shared__ float pacc[NP][NTT];
  const float mu = ws[OFF_MU];
  for (int i = t; i < NP; i += TPB)
    vloc[i] = (i < NSUP) ? (ws[OFF_R1 + i*NW + a] - ws[OFF_DNU + i]) : 0.0f;
  __syncthreads();
  if (act) {
    const float* Xa = ws + OFF_X + a*XSZ;
    const int cb = 8*tc;
#pragma unroll
    for (int r = 0; r < 8; ++r) {
      const float4* src = (const float4*)(Xa + (8*tr+r)*NP + cb);
      const float4 v0 = src[0], v1 = src[1];
      pacc[8*tr+r][tc] =
          v0.x*vloc[cb+0] + v0.y*vloc[cb+1] + v0.z*vloc[cb+2] + v0.w*vloc[cb+3]
        + v1.x*vloc[cb+4] + v1.y*vloc[cb+5] + v1.z*vloc[cb+6] + v1.w*vloc[cb+7];
    }
  }
  __syncthreads();
  if (t < NSUP) {
    float dzv = 0.0f;
    for (int q = 0; q < NTT; ++q) dzv += pacc[t][q];
    const float svv = ws[OFF_S + t*NW+a], lvv = ws[OFF_LAM + t*NW+a];
    const float rc  = svv*lvv - SIGMA*mu;
    const float dlv = (lvv*dzv - rc)/svv;
    ws[OFF_DZ + t*NW+a]   = dzv;
    ws[OFF_DLAM + t*NW+a] = dlv;
    unsigned* slot = (unsigned*)(ws) + OFF_ALPHA;
    const float dsv = -dzv;
    if (dsv < 0.0f) atomicMin(slot, __float_as_uint(-svv/dsv));
    if (dlv < 0.0f) atomicMin(slot, __float_as_uint(-lvv/dlv));
  }
}

// ---------------- K4: alpha, update z,s,lam,nu; next mu, rp --------------------------
__global__ __launch_bounds__(1024) void kqp4(float* __restrict__ ws) {
  const int t = threadIdx.x;
  __shared__ float zsh[NVAR];
  __shared__ float red[1024];
  const float am = __uint_as_float(((unsigned*)ws)[OFF_ALPHA]);
  const float alpha = fminf(1.0f, 0.99f * am);
  float part = 0.0f;
  for (int idx = t; idx < NVAR; idx += 1024) {
    const float dzv = ws[OFF_DZ + idx], dlv = ws[OFF_DLAM + idx];
    const float zn = ws[OFF_Z + idx]   + alpha*dzv;
    const float sn = ws[OFF_S + idx]   - alpha*dzv;
    const float ln = ws[OFF_LAM + idx] + alpha*dlv;
    ws[OFF_Z+idx]=zn; ws[OFF_S+idx]=sn; ws[OFF_LAM+idx]=ln;
    zsh[idx] = zn;
    part += sn*ln;
  }
  if (t < NSUP) ws[OFF_NU + t] += alpha * ws[OFF_DNU + t];
  red[t] = part;
  __syncthreads();
  for (int off = 512; off > 0; off >>= 1) {
    if (t < off) red[t] += red[t + off];
    __syncthreads();
  }
  if (t == 0) ws[OFF_MU] = red[0] / (float)NVAR;
  if (t < NSUP) {
    float rpv = 0.0f;
#pragma unroll
    for (int a = 0; a < NW; ++a) rpv += zsh[t*NW+a];
    ws[OFF_RP + t] = rpv;
  }
}

// ---------------- Wt[w][d] = scale * sum_s support[s][d] * z[s*10+w] -----------------
__global__ __launch_bounds__(1024) void k_wt(const float* __restrict__ feat,
                                             const float* __restrict__ scale,
                                             float* __restrict__ ws) {
  const int w = blockIdx.x;
  const int dd = threadIdx.x;
  float acc = 0.0f;
  for (int ss = 0; ss < NSUP; ++ss)
    acc += feat[ss*DIM + dd] * ws[OFF_Z + ss*NW + w];
  ws[OFF_WT + w*DIM + dd] = acc * scale[0];
}

// ---------------- logits + log_softmax + loss partials (wave per query row) ----------
__global__ __launch_bounds__(256) void k_logits(const float* __restrict__ feat,
                                                const int* __restrict__ labq,
                                                float* __restrict__ out,
                                                float* __restrict__ ws) {
  const int t = threadIdx.x;
  const int wv = t >> 6, l = t & 63;
  const int q = blockIdx.x*4 + wv;
  __shared__ float wtl[NW][DIM];
  __shared__ float lpart[4];
  for (int idx = t; idx < NW*DIM; idx += 256) wtl[idx >> 10][idx & 1023] = ws[OFF_WT + idx];
  __syncthreads();
  const float* qrow = feat + (size_t)(NSUP + q)*DIM;
  float acc[NW];
#pragma unroll
  for (int w = 0; w < NW; ++w) acc[w] = 0.0f;
#pragma unroll
  for (int c = 0; c < 4; ++c) {
    const float4 qv = *(const float4*)(qrow + c*256 + 4*l);
#pragma unroll
    for (int w = 0; w < NW; ++w) {
      const float4 wvv = *(const float4*)(&wtl[w][c*256 + 4*l]);
      acc[w] += qv.x*wvv.x + qv.y*wvv.y + qv.z*wvv.z + qv.w*wvv.w;
    }
  }
#pragma unroll
  for (int w = 0; w < NW; ++w) {
#pragma unroll
    for (int off = 32; off > 0; off >>= 1)
      acc[w] += __shfl_xor(acc[w], off, 64);
  }
  float m = acc[0];
#pragma unroll
  for (int w = 1; w < NW; ++w) m = fmaxf(m, acc[w]);
  float se = 0.0f;
#pragma unroll
  for (int w = 0; w < NW; ++w) se += expf(acc[w]-m);
  const float lse = m + logf(se);
  const int y = labq[q];
  if (l == 0) {
    float lpy = 0.0f;
#pragma unroll
    for (int w = 0; w < NW; ++w) {
      const float lp = acc[w] - lse;
      out[q*NW + w] = lp;
      if (w == y) lpy = lp;
    }
    lpart[wv] = -lpy;
  }
  __syncthreads();
  if (t == 0) ws[OFF_LP + blockIdx.x] = lpart[0]+lpart[1]+lpart[2]+lpart[3];
}

__global__ __launch_bounds__(1024) void k_loss(float* __restrict__ out, const float* __restrict__ ws) {
  const int t = threadIdx.x;
  __shared__ float red[1024];
  red[t] = ws[OFF_LP + t] + ws[OFF_LP + 1024 + t];
  __syncthreads();
  for (int off = 512; off > 0; off >>= 1) {
    if (t < off) red[t] += red[t + off];
    __syncthreads();
  }
  if (t == 0) out[NQ*NW] = red[0] / (float)NQ;
}

extern "C" void kernel_launch(void* const* d_in, const int* in_sizes, int n_in,
                              void* d_out, int out_size, void* d_ws, size_t ws_size,
                              hipStream_t stream) {
  const float* feat  = (const float*)d_in[0];
  const int*   labS  = (const int*)d_in[1];
  const int*   labQ  = (const int*)d_in[2];
  const float* scale = (const float*)d_in[3];
  float* ws  = (float*)d_ws;
  float* out = (float*)d_out;

  k_gram<<<100, 256, 0, stream>>>(feat, ws);
  kinit<<<1, 1024, 0, stream>>>(labS, ws);
  for (int it = 0; it < 15; ++it) {
    kqp1<<<NW, TPB, 0, stream>>>(labS, ws);
    k_sum<<<32, 256, 0, stream>>>(ws);
    kqp2<<<1,  TPB, 0, stream>>>(ws);
    kqp3<<<NW, TPB, 0, stream>>>(ws);
    kqp4<<<1, 1024, 0, stream>>>(ws);
  }
  k_wt<<<NW, 1024, 0, stream>>>(feat, scale, ws);
  k_logits<<<NQ/4, 256, 0, stream>>>(feat, labQ, out, ws);
  k_loss<<<1, 1024, 0, stream>>>(out, ws);
}